// Round 7
// baseline (5247.984 us; speedup 1.0000x reference)
//
#include <hip/hip_runtime.h>
#include <cstddef>

// Problem constants
#define Bsz  4096
#define Sseq 16
#define Gdim 128
#define Edim 256
#define Hdim 512
#define H4   2048
#define Psteps 16
#define BK   16

typedef short bfrag8 __attribute__((ext_vector_type(8)));   // 8 bf16 (4 VGPR)
typedef float f32x4  __attribute__((ext_vector_type(4)));   // MFMA acc

// Exact 3-way bf16 split of fp32 (truncation; residuals exactly representable:
// 24 mantissa bits = 8+8+8). a == hi+mid+lo exactly (normal range).
__device__ __forceinline__ void split3(float f, unsigned short& h,
                                       unsigned short& m, unsigned short& l) {
    unsigned u = __float_as_uint(f);
    h = (unsigned short)(u >> 16);
    float r1 = f - __uint_as_float(u & 0xffff0000u);
    unsigned u1 = __float_as_uint(r1);
    m = (unsigned short)(u1 >> 16);
    float r2 = r1 - __uint_as_float(u1 & 0xffff0000u);
    l = (unsigned short)(__float_as_uint(r2) >> 16);
}

// ---------------------------------------------------------------------------
// Fold kernel: gate-interleaved (row c = j*4+gate) weight prep, emitting
// bf16 hi/mid/lo planes for the MFMA path.
// ---------------------------------------------------------------------------
__global__ void fold_kernel(const float* __restrict__ encWih,
                            const float* __restrict__ encWhh,
                            const float* __restrict__ enc_b,
                            const float* __restrict__ decWih,
                            const float* __restrict__ decWhh,
                            const float* __restrict__ dec_b,
                            const float* __restrict__ embW,
                            const float* __restrict__ dec0,
                            unsigned short* __restrict__ encEh,
                            unsigned short* __restrict__ encEm,
                            unsigned short* __restrict__ encEl,
                            unsigned short* __restrict__ encWh,
                            unsigned short* __restrict__ encWm,
                            unsigned short* __restrict__ encWl,
                            unsigned short* __restrict__ decEh,
                            unsigned short* __restrict__ decEm,
                            unsigned short* __restrict__ decEl,
                            unsigned short* __restrict__ decWh,
                            unsigned short* __restrict__ decWm,
                            unsigned short* __restrict__ decWl,
                            float* __restrict__ encBI, float* __restrict__ decBI,
                            float* __restrict__ v0bI) {
    const int o = blockIdx.x;            // original row 0..2047 (gate*512 + j)
    const int gate = o >> 9, j = o & 511;
    const int c = j * 4 + gate;          // interleaved row
    const int g = threadIdx.x;           // 0..127
    float se = 0.f, sd = 0.f;
    for (int e = 0; e < Edim; ++e) {
        float w = embW[e * Gdim + g];
        se += encWih[(size_t)o * Edim + e] * w;
        sd += decWih[(size_t)o * Edim + e] * w;
    }
    unsigned short h, m, l;
    split3(se, h, m, l);
    encEh[(size_t)c * Gdim + g] = h; encEm[(size_t)c * Gdim + g] = m;
    encEl[(size_t)c * Gdim + g] = l;
    split3(sd, h, m, l);
    decEh[(size_t)c * Gdim + g] = h; decEm[(size_t)c * Gdim + g] = m;
    decEl[(size_t)c * Gdim + g] = l;
    for (int k = g; k < Hdim; k += Gdim) {
        split3(encWhh[(size_t)o * Hdim + k], h, m, l);
        encWh[(size_t)c * Hdim + k] = h; encWm[(size_t)c * Hdim + k] = m;
        encWl[(size_t)c * Hdim + k] = l;
        split3(decWhh[(size_t)o * Hdim + k], h, m, l);
        decWh[(size_t)c * Hdim + k] = h; decWm[(size_t)c * Hdim + k] = m;
        decWl[(size_t)c * Hdim + k] = l;
    }
    if (g == 0) {
        encBI[c] = enc_b[o];
        decBI[c] = dec_b[o];
        float s = dec_b[o];
        for (int e = 0; e < Edim; ++e) s += decWih[(size_t)o * Edim + e] * dec0[e];
        v0bI[c] = s;
    }
}

// ---------------------------------------------------------------------------
// MFMA gates GEMM + fused LSTM epilogue, fp32-exact via bf16x6 emulation.
// Round-7: occupancy via geometry, keeping the proven round-4 body. Round-4/5
// plateaued at 84-88us with 35% dual-idle at 2 waves/SIMD (grid 512 = the
// occupancy cap; VGPR 124 already allowed 4/SIMD). New geometry:
//   - 2-wave blocks (128 thr), block tile 64n x 64m, wave tile 64n x 32m
//     (acc 4x2); grid (64,32) = 2048 blocks = 8 blocks/CU = 16 waves/CU
//     = 4 waves/SIMD.
//   - LDS stages only hi+mid weight planes (16 KB/block -> 8 blocks fit in
//     160 KB); the lo plane is loaded direct from global (L3-resident, 1 of
//     6 MFMAs, TLP now hides it).
//   - activation loads + split3 in-phase (round-4 style; A/B prefetch dropped
//     to stay under the 128-VGPR 4-wave cliff).
// Same chunk order, same split3 values, same 6-MFMA order, LDS roundtrip
// preserves bits -> output bit-identical.
// ---------------------------------------------------------------------------
__global__ __launch_bounds__(128) void gates_mfma(
    const unsigned short* __restrict__ Wh1, const unsigned short* __restrict__ Wm1,
    const unsigned short* __restrict__ Wl1, int K1,
    const float* __restrict__ X, int ldx,
    const int* __restrict__ gather, int gmul,
    const unsigned short* __restrict__ Wh2, const unsigned short* __restrict__ Wm2,
    const unsigned short* __restrict__ Wl2, int K2,
    const float* __restrict__ Hin,
    const float* __restrict__ biasI,
    const float* __restrict__ c_in, float* __restrict__ h_out,
    float* __restrict__ c_out, int czero)
{
    __shared__ __align__(16) unsigned short wlds[2 * 2 * 2048]; // 16 KB

    const int tid = threadIdx.x;                 // 0..127
    const int wv = tid >> 6, lane = tid & 63;
    const int lm = lane & 15, quad = lane >> 4;
    const int c0 = blockIdx.y * 64;              // n-panel base (64 rows)
    const int mB = blockIdx.x * 64 + wv * 32;    // wave batch tile base

    // per-lane activation row pointers (2 m-tiles)
    int mrow[2];
    const float* xr[2];
    const float* hr[2];
#pragma unroll
    for (int tm = 0; tm < 2; ++tm) {
        int m = mB + tm * 16 + lm;
        mrow[tm] = m;
        if (X) {
            size_t off = (size_t)m * ldx;
            if (gather) off += (size_t)gather[m] * gmul;
            xr[tm] = X + off;
        }
        if (Hin) hr[tm] = Hin + (size_t)m * K2;
    }

    // lo-plane weight row offsets (global direct, element units)
    int aRl1[4], aRl2[4];
#pragma unroll
    for (int tn = 0; tn < 4; ++tn) {
        int n = c0 + tn * 16 + lm;
        aRl1[tn] = n * K1;
        aRl2[tn] = n * K2;
    }

    // ---- staging geometry: 64 rows x 32k, hi+mid planes, 128 threads ----
    // issue i in {0,1}: seg = i*2+wv (0..3), rows seg*16 + lane/4
    int srow[2], sqs[2];
#pragma unroll
    for (int i = 0; i < 2; ++i) {
        const int seg = i * 2 + wv;
        const int r = seg * 16 + (lane >> 2);
        srow[i] = r;
        sqs[i] = (lane & 3) ^ ((r >> 1) & 3);    // pre-swizzled source chunk
    }
    size_t roff1[2], roff2[2];
#pragma unroll
    for (int i = 0; i < 2; ++i) {
        roff1[i] = (size_t)(c0 + srow[i]) * K1 + (size_t)(sqs[i] * 8);
        roff2[i] = (size_t)(c0 + srow[i]) * K2 + (size_t)(sqs[i] * 8);
    }

    // ds_read fragment offsets (ushort units; constant across chunks)
    int boffW[4];
#pragma unroll
    for (int tn = 0; tn < 4; ++tn) {
        const int r = tn * 16 + lm;
        boffW[tn] = r * 32 + ((quad ^ ((r >> 1) & 3)) * 8);
    }

    // stage hi+mid weight planes for absolute chunk kcN into wlds[buf]
    auto stage = [&](int kcN, int buf) {
        const bool nX = kcN < K1;
        const int kb = nX ? kcN : kcN - K1;
#pragma unroll
        for (int i = 0; i < 2; ++i) {
            const int seg = i * 2 + wv;
            unsigned short* lb = wlds + buf * 4096 + seg * 512;
            const unsigned short* gh = (nX ? Wh1 + roff1[i] : Wh2 + roff2[i]) + kb;
            const unsigned short* gm = (nX ? Wm1 + roff1[i] : Wm2 + roff2[i]) + kb;
            __builtin_amdgcn_global_load_lds(
                (const __attribute__((address_space(1))) void*)gh,
                (__attribute__((address_space(3))) void*)(lb), 16, 0, 0);
            __builtin_amdgcn_global_load_lds(
                (const __attribute__((address_space(1))) void*)gm,
                (__attribute__((address_space(3))) void*)(lb + 2048), 16, 0, 0);
        }
    };

    f32x4 acc[4][2];
#pragma unroll
    for (int i = 0; i < 4; ++i)
#pragma unroll
        for (int j = 0; j < 2; ++j) acc[i][j] = (f32x4){0.f, 0.f, 0.f, 0.f};

    const int KT = K1 + K2;   // 128, 512 or 640
    stage(0, 0);
    int cur = 0;

    for (int kc = 0; kc < KT; kc += 32) {
        __syncthreads();                       // wlds[cur] staged & readable
        if (kc + 32 < KT) stage(kc + 32, cur ^ 1);

        const bool inX = kc < K1;
        const int kk = (inX ? kc : kc - K1) + quad * 8;

        // lo weight fragments direct from global (L3-resident)
        bfrag8 al[4];
#pragma unroll
        for (int tn = 0; tn < 4; ++tn)
            al[tn] = *(const bfrag8*)((inX ? Wl1 + aRl1[tn] : Wl2 + aRl2[tn]) + kk);

        // hi/mid weight fragments from LDS (swizzled ds_read_b128)
        const unsigned short* bufp = wlds + cur * 4096;
        bfrag8 ah[4], am4[4];
#pragma unroll
        for (int tn = 0; tn < 4; ++tn) {
            ah[tn]  = *(const bfrag8*)(bufp + boffW[tn]);
            am4[tn] = *(const bfrag8*)(bufp + 2048 + boffW[tn]);
        }

#pragma unroll
        for (int tm = 0; tm < 2; ++tm) {
            const float* p = (inX ? xr[tm] : hr[tm]) + kk;
            float a8[8];
            *(float4*)&a8[0] = *(const float4*)(p);
            *(float4*)&a8[4] = *(const float4*)(p + 4);
            bfrag8 bh, bm, bl;
#pragma unroll
            for (int j = 0; j < 8; ++j) {
                unsigned short h, m, l;
                split3(a8[j], h, m, l);
                bh[j] = (short)h; bm[j] = (short)m; bl[j] = (short)l;
            }
#pragma unroll
            for (int tn = 0; tn < 4; ++tn) {
                f32x4 c = acc[tn][tm];
                c = __builtin_amdgcn_mfma_f32_16x16x32_bf16(ah[tn], bl, c, 0, 0, 0);
                c = __builtin_amdgcn_mfma_f32_16x16x32_bf16(al[tn], bh, c, 0, 0, 0);
                c = __builtin_amdgcn_mfma_f32_16x16x32_bf16(am4[tn], bm, c, 0, 0, 0);
                c = __builtin_amdgcn_mfma_f32_16x16x32_bf16(ah[tn], bm, c, 0, 0, 0);
                c = __builtin_amdgcn_mfma_f32_16x16x32_bf16(am4[tn], bh, c, 0, 0, 0);
                c = __builtin_amdgcn_mfma_f32_16x16x32_bf16(ah[tn], bh, c, 0, 0, 0);
                acc[tn][tm] = c;
            }
        }
        cur ^= 1;
    }

    // fused LSTM epilogue: lane's 4 acc regs = gates i,f,g,o of unit j
#pragma unroll
    for (int tn = 0; tn < 4; ++tn) {
        const int nb = c0 + tn * 16 + quad * 4;
        float4 bb = *(const float4*)(biasI + nb);
        const int j = nb >> 2;
#pragma unroll
        for (int tm = 0; tm < 2; ++tm) {
            const size_t idx = (size_t)mrow[tm] * Hdim + j;
            float gi = acc[tn][tm][0] + bb.x;
            float gf = acc[tn][tm][1] + bb.y;
            float gg = acc[tn][tm][2] + bb.z;
            float go = acc[tn][tm][3] + bb.w;
            float si = 1.f / (1.f + expf(-gi));
            float sf = 1.f / (1.f + expf(-gf));
            float so = 1.f / (1.f + expf(-go));
            float co = czero ? 0.f : c_in[idx];
            float cn = si * tanhf(gg) + sf * co;
            c_out[idx] = cn;
            h_out[idx] = so * tanhf(cn);
        }
    }
}

// ---------------------------------------------------------------------------
// Small fp32 GEMM: C = A @ W^T + bias (4096x512, K=512). 64x64 tile, 256
// threads, 2x2 waves, per-lane 4x4 (52 VGPR, proven). Grid (8,64)=512=2/CU.
// Used for u2 (Wref2) and qp (Wq2).
// ---------------------------------------------------------------------------
__global__ __launch_bounds__(256, 4) void gemm_sm(const float* __restrict__ A,
                                                  const float* __restrict__ W,
                                                  const float* __restrict__ bias,
                                                  float* __restrict__ C, int ldc)
{
    __shared__ float As[BK][64];
    __shared__ float Bs[BK][64];
    const int tid = threadIdx.x;
    const int rowBase = blockIdx.y * 64;
    const int colBase = blockIdx.x * 64;
    const int wv = tid >> 6;
    const int waveX = wv & 1, waveY = wv >> 1;
    const int lane = tid & 63;
    const int lx = lane & 7, ly = lane >> 3;
    const int rOff = waveY * 32 + ly * 4;
    const int cOff = waveX * 32 + lx * 4;

    const int ra = tid & 63;
    const int ka = (tid >> 6) * 4;
    const float* arow = A + (size_t)(rowBase + ra) * Hdim + ka;
    const float* brow = W + (size_t)(colBase + ra) * Hdim + ka;

    float4 aR, bR;
    float acc[4][4];
#pragma unroll
    for (int i = 0; i < 4; ++i)
#pragma unroll
        for (int j = 0; j < 4; ++j) acc[i][j] = 0.f;

    aR = *(const float4*)(arow);
    bR = *(const float4*)(brow);
    for (int kt = 0; kt < Hdim; kt += BK) {
        __syncthreads();
        As[ka + 0][ra] = aR.x; As[ka + 1][ra] = aR.y;
        As[ka + 2][ra] = aR.z; As[ka + 3][ra] = aR.w;
        Bs[ka + 0][ra] = bR.x; Bs[ka + 1][ra] = bR.y;
        Bs[ka + 2][ra] = bR.z; Bs[ka + 3][ra] = bR.w;
        __syncthreads();
        if (kt + BK < Hdim) {
            aR = *(const float4*)(arow + kt + BK);
            bR = *(const float4*)(brow + kt + BK);
        }
#pragma unroll
        for (int kk = 0; kk < BK; ++kk) {
            float4 av = *(const float4*)&As[kk][rOff];
            float4 bv = *(const float4*)&Bs[kk][cOff];
            const float* ap = (const float*)&av;
            const float* bp = (const float*)&bv;
#pragma unroll
            for (int i = 0; i < 4; ++i)
#pragma unroll
                for (int j = 0; j < 4; ++j) acc[i][j] += ap[i] * bp[j];
        }
    }

    float4 bb = *(const float4*)(bias + colBase + cOff);
#pragma unroll
    for (int i = 0; i < 4; ++i) {
        const int row = rowBase + rOff + i;
        float4 o;
        o.x = acc[i][0] + bb.x;
        o.y = acc[i][1] + bb.y;
        o.z = acc[i][2] + bb.z;
        o.w = acc[i][3] + bb.w;
        *(float4*)(C + (size_t)row * ldc + colBase + cOff) = o;
    }
}

// ---------------------------------------------------------------------------
// Attention + log-softmax + argmax + state update.
// ---------------------------------------------------------------------------
__global__ __launch_bounds__(256) void attn_step(const float* __restrict__ qp,
                                                 const float* __restrict__ u2,
                                                 const float* __restrict__ Vec2,
                                                 float* __restrict__ mask,
                                                 float* __restrict__ ll_ws,
                                                 int* __restrict__ nxt,
                                                 float* __restrict__ out_map,
                                                 float* __restrict__ out_ll,
                                                 int step, int node) {
    const int b = blockIdx.x;
    __shared__ float qpS[Hdim];
    __shared__ float vS[Hdim];
    __shared__ float logitS[Sseq];
    const int tid = threadIdx.x;
    qpS[tid]       = qp[(size_t)b * Hdim + tid];
    qpS[tid + 256] = qp[(size_t)b * Hdim + 256 + tid];
    vS[tid]        = Vec2[tid];
    vS[tid + 256]  = Vec2[256 + tid];
    __syncthreads();

    const int wave = tid >> 6, lane = tid & 63;
    for (int si = 0; si < 4; ++si) {
        int s = wave * 4 + si;
        const float* u2p = u2 + ((size_t)b * Sseq + s) * Hdim;
        float sum = 0.f;
#pragma unroll
        for (int i = 0; i < 8; ++i) {
            int hh = lane + i * 64;
            sum += vS[hh] * tanhf(qpS[hh] + u2p[hh]);
        }
        for (int off = 32; off > 0; off >>= 1) sum += __shfl_down(sum, off);
        if (lane == 0) {
            float pen = step ? mask[b * Sseq + s] * 1e8f : 0.f;
            logitS[s] = 10.f * sum - pen;
        }
    }
    __syncthreads();

    if (tid == 0) {
        float mx = logitS[0];
        int am = 0;
        for (int s = 1; s < Sseq; ++s)
            if (logitS[s] > mx) { mx = logitS[s]; am = s; }
        float se = 0.f;
        for (int s = 0; s < Sseq; ++s) se += expf(logitS[s] - mx);
        float lp = -logf(se);
        float llv = (step ? ll_ws[b] : 0.f) + lp;
        ll_ws[b] = llv;
        out_ll[b] = llv;
        nxt[b] = am;
        if (step == 0) {
            for (int s = 0; s < Sseq; ++s) mask[b * Sseq + s] = (s == am) ? 1.f : 0.f;
        } else {
            mask[b * Sseq + am] += 1.f;
        }
        out_map[b * Sseq + am] = (float)node;
    }
}

// ---------------------------------------------------------------------------
extern "C" void kernel_launch(void* const* d_in, const int* in_sizes, int n_in,
                              void* d_out, int out_size, void* d_ws, size_t ws_size,
                              hipStream_t stream) {
    const float* x       = (const float*)d_in[0];
    const float* emb_W   = (const float*)d_in[1];
    const float* enc_Wih = (const float*)d_in[2];
    const float* enc_Whh = (const float*)d_in[3];
    const float* enc_b   = (const float*)d_in[4];
    const float* dec_Wih = (const float*)d_in[5];
    const float* dec_Whh = (const float*)d_in[6];
    const float* dec_b   = (const float*)d_in[7];
    const float* Wq2     = (const float*)d_in[8];
    const float* bq2     = (const float*)d_in[9];
    const float* Wref2   = (const float*)d_in[10];
    const float* bref2   = (const float*)d_in[11];
    const float* Vec2    = (const float*)d_in[12];
    const float* dec0    = (const float*)d_in[13];

    // workspace layout — ~192 MB
    float* ws      = (float*)d_ws;
    float* u2      = ws;                                   // B*S*H fp32
    float* h0      = u2 + (size_t)Bsz * Sseq * Hdim;       // B*H each
    float* c0      = h0 + (size_t)Bsz * Hdim;
    float* h1      = c0 + (size_t)Bsz * Hdim;
    float* c1      = h1 + (size_t)Bsz * Hdim;
    float* qp      = c1 + (size_t)Bsz * Hdim;
    float* mask    = qp + (size_t)Bsz * Hdim;              // B*S
    float* ll      = mask + (size_t)Bsz * Sseq;            // B
    int*   nxt     = (int*)(ll + Bsz);                     // B
    float* encBI   = (float*)(nxt + Bsz);                  // 2048 each
    float* decBI   = encBI + H4;
    float* v0bI    = decBI + H4;
    // bf16 weight planes (ushort)
    unsigned short* us = (unsigned short*)(v0bI + H4);
    unsigned short* encEh = us;                       us += (size_t)H4 * Gdim;
    unsigned short* encEm = us;                       us += (size_t)H4 * Gdim;
    unsigned short* encEl = us;                       us += (size_t)H4 * Gdim;
    unsigned short* encWh = us;                       us += (size_t)H4 * Hdim;
    unsigned short* encWm = us;                       us += (size_t)H4 * Hdim;
    unsigned short* encWl = us;                       us += (size_t)H4 * Hdim;
    unsigned short* decEh = us;                       us += (size_t)H4 * Gdim;
    unsigned short* decEm = us;                       us += (size_t)H4 * Gdim;
    unsigned short* decEl = us;                       us += (size_t)H4 * Gdim;
    unsigned short* decWh = us;                       us += (size_t)H4 * Hdim;
    unsigned short* decWm = us;                       us += (size_t)H4 * Hdim;
    unsigned short* decWl = us;                       us += (size_t)H4 * Hdim;

    float* out_map = (float*)d_out;                        // B*P floats
    float* out_ll  = out_map + (size_t)Bsz * Psteps;       // B floats

    static const int nodes[Psteps] = {0,0,0,0, 1,1,1,1, 2,2,2,2, 3,3,3,3};

    fold_kernel<<<H4, Gdim, 0, stream>>>(enc_Wih, enc_Whh, enc_b,
                                         dec_Wih, dec_Whh, dec_b,
                                         emb_W, dec0,
                                         encEh, encEm, encEl, encWh, encWm, encWl,
                                         decEh, decEm, decEl, decWh, decWm, decWl,
                                         encBI, decBI, v0bI);

    const dim3 gBig(64, 32);    // m-blocks x n-blocks = 2048 = 8/CU
    const dim3 gSm(8, 64);      // 512 blocks = 2/CU

    // ---- encoder: 16 fused LSTM steps + u2[t] projection of h(t) ----
    for (int t = 0; t < Sseq; ++t) {
        float* ho = (t & 1) ? h0 : h1;
        float* co = (t & 1) ? c0 : c1;
        const float* hi = (t & 1) ? h1 : h0;
        const float* ci = (t & 1) ? c1 : c0;
        if (t == 0) {
            gates_mfma<<<gBig, 128, 0, stream>>>(
                encEh, encEm, encEl, Gdim,
                x, Sseq * Gdim, nullptr, 0,
                nullptr, nullptr, nullptr, 0, nullptr,
                encBI, ci, ho, co, 1);
        } else {
            gates_mfma<<<gBig, 128, 0, stream>>>(
                encEh, encEm, encEl, Gdim,
                x + t * Gdim, Sseq * Gdim, nullptr, 0,
                encWh, encWm, encWl, Hdim, hi,
                encBI, ci, ho, co, 0);
        }
        gemm_sm<<<gSm, 256, 0, stream>>>(ho, Wref2, bref2,
                                         u2 + (size_t)t * Hdim, Sseq * Hdim);
    }

    // ---- decoder: 16 autoregressive steps ----
    for (int p = 0; p < Psteps; ++p) {
        const int u = Sseq + p;
        float* ho = (u & 1) ? h0 : h1;
        float* co = (u & 1) ? c0 : c1;
        const float* hi = (u & 1) ? h1 : h0;
        const float* ci = (u & 1) ? c1 : c0;
        if (p == 0) {
            gates_mfma<<<gBig, 128, 0, stream>>>(
                nullptr, nullptr, nullptr, 0,
                nullptr, 0, nullptr, 0,
                decWh, decWm, decWl, Hdim, hi,
                v0bI, ci, ho, co, 0);
        } else {
            gates_mfma<<<gBig, 128, 0, stream>>>(
                decEh, decEm, decEl, Gdim,
                x, Sseq * Gdim, nxt, Gdim,
                decWh, decWm, decWl, Hdim, hi,
                decBI, ci, ho, co, 0);
        }
        gemm_sm<<<gSm, 256, 0, stream>>>(ho, Wq2, bq2, qp, Hdim);
        attn_step<<<Bsz, 256, 0, stream>>>(qp, u2, Vec2, mask, ll, nxt,
                                           out_map, out_ll, p, nodes[p]);
    }
}

// Round 8
// 4562.452 us; speedup vs baseline: 1.1503x; 1.1503x over previous
//
#include <hip/hip_runtime.h>
#include <cstddef>

// Problem constants
#define Bsz  4096
#define Sseq 16
#define Gdim 128
#define Edim 256
#define Hdim 512
#define H4   2048
#define Psteps 16
#define BK   16

typedef short bfrag8 __attribute__((ext_vector_type(8)));   // 8 bf16 (4 VGPR)
typedef unsigned short u16x8 __attribute__((ext_vector_type(8)));
typedef float f32x4  __attribute__((ext_vector_type(4)));   // MFMA acc

// Exact 3-way bf16 split of fp32 (truncation; residuals exactly representable:
// 24 mantissa bits = 8+8+8). a == hi+mid+lo exactly (normal range).
__device__ __forceinline__ void split3(float f, unsigned short& h,
                                       unsigned short& m, unsigned short& l) {
    unsigned u = __float_as_uint(f);
    h = (unsigned short)(u >> 16);
    float r1 = f - __uint_as_float(u & 0xffff0000u);
    unsigned u1 = __float_as_uint(r1);
    m = (unsigned short)(u1 >> 16);
    float r2 = r1 - __uint_as_float(u1 & 0xffff0000u);
    l = (unsigned short)(__float_as_uint(r2) >> 16);
}

// ---------------------------------------------------------------------------
// Fold kernel: gate-interleaved (row c = j*4+gate) weight prep, emitting
// bf16 hi/mid/lo planes for the MFMA path.
// ---------------------------------------------------------------------------
__global__ void fold_kernel(const float* __restrict__ encWih,
                            const float* __restrict__ encWhh,
                            const float* __restrict__ enc_b,
                            const float* __restrict__ decWih,
                            const float* __restrict__ decWhh,
                            const float* __restrict__ dec_b,
                            const float* __restrict__ embW,
                            const float* __restrict__ dec0,
                            unsigned short* __restrict__ encEh,
                            unsigned short* __restrict__ encEm,
                            unsigned short* __restrict__ encEl,
                            unsigned short* __restrict__ encWh,
                            unsigned short* __restrict__ encWm,
                            unsigned short* __restrict__ encWl,
                            unsigned short* __restrict__ decEh,
                            unsigned short* __restrict__ decEm,
                            unsigned short* __restrict__ decEl,
                            unsigned short* __restrict__ decWh,
                            unsigned short* __restrict__ decWm,
                            unsigned short* __restrict__ decWl,
                            float* __restrict__ encBI, float* __restrict__ decBI,
                            float* __restrict__ v0bI) {
    const int o = blockIdx.x;            // original row 0..2047 (gate*512 + j)
    const int gate = o >> 9, j = o & 511;
    const int c = j * 4 + gate;          // interleaved row
    const int g = threadIdx.x;           // 0..127
    float se = 0.f, sd = 0.f;
    for (int e = 0; e < Edim; ++e) {
        float w = embW[e * Gdim + g];
        se += encWih[(size_t)o * Edim + e] * w;
        sd += decWih[(size_t)o * Edim + e] * w;
    }
    unsigned short h, m, l;
    split3(se, h, m, l);
    encEh[(size_t)c * Gdim + g] = h; encEm[(size_t)c * Gdim + g] = m;
    encEl[(size_t)c * Gdim + g] = l;
    split3(sd, h, m, l);
    decEh[(size_t)c * Gdim + g] = h; decEm[(size_t)c * Gdim + g] = m;
    decEl[(size_t)c * Gdim + g] = l;
    for (int k = g; k < Hdim; k += Gdim) {
        split3(encWhh[(size_t)o * Hdim + k], h, m, l);
        encWh[(size_t)c * Hdim + k] = h; encWm[(size_t)c * Hdim + k] = m;
        encWl[(size_t)c * Hdim + k] = l;
        split3(decWhh[(size_t)o * Hdim + k], h, m, l);
        decWh[(size_t)c * Hdim + k] = h; decWm[(size_t)c * Hdim + k] = m;
        decWl[(size_t)c * Hdim + k] = l;
    }
    if (g == 0) {
        encBI[c] = enc_b[o];
        decBI[c] = dec_b[o];
        float s = dec_b[o];
        for (int e = 0; e < Edim; ++e) s += decWih[(size_t)o * Edim + e] * dec0[e];
        v0bI[c] = s;
    }
}

// ---------------------------------------------------------------------------
// Coalesced activation split: h (fp32, row-major) -> hi/mid/lo bf16 planes,
// 8 elems/thread, 16B vector stores. This is the round-1 idea with the
// producer fixed: round-1 fused the plane store into the gates epilogue and
// its scattered 2B stores cost +63 MB of write amplification; here every
// store is a full 16B coalesced ushort8. Values are bit-identical to
// in-kernel split3.
// ---------------------------------------------------------------------------
__global__ __launch_bounds__(256) void split_planes(
    const float* __restrict__ src,
    unsigned short* __restrict__ ph, unsigned short* __restrict__ pm,
    unsigned short* __restrict__ pl)
{
    const int i = blockIdx.x * 256 + threadIdx.x;   // 8 elems per thread
    const size_t base = (size_t)i * 8;
    float a8[8];
    *(float4*)&a8[0] = *(const float4*)(src + base);
    *(float4*)&a8[4] = *(const float4*)(src + base + 4);
    u16x8 vh, vm, vl;
#pragma unroll
    for (int j = 0; j < 8; ++j) {
        unsigned short h, m, l;
        split3(a8[j], h, m, l);
        vh[j] = h; vm[j] = m; vl[j] = l;
    }
    *(u16x8*)(ph + base) = vh;
    *(u16x8*)(pm + base) = vm;
    *(u16x8*)(pl + base) = vl;
}

// ---------------------------------------------------------------------------
// MFMA gates GEMM + fused LSTM epilogue, fp32-exact via bf16x6 emulation.
// Round-8: round-4 geometry (the best measured: 128n x 128m block, 4 waves,
// 64x64/wave, grid (32,16)=512, 48 KB LDS weight double-buffer via
// global_load_lds). ONE change: H-part activations (16 of 20 chunks) are
// consumed as PRE-SPLIT bf16 planes written coalesced by split_planes --
// removing ~80% of the per-chunk split3+repack VALU stream, which was
// recomputed redundantly by all 16 n-panel blocks. X-part (4 chunks, incl.
// the decode gather) keeps fp32 loads + in-kernel split3. Same chunk order,
// same operand bits, same 6-MFMA order -> output bit-identical.
// ---------------------------------------------------------------------------
__global__ __launch_bounds__(256) void gates_mfma(
    const unsigned short* __restrict__ Wh1, const unsigned short* __restrict__ Wm1,
    const unsigned short* __restrict__ Wl1, int K1,
    const float* __restrict__ X, int ldx,
    const int* __restrict__ gather, int gmul,
    const unsigned short* __restrict__ Wh2, const unsigned short* __restrict__ Wm2,
    const unsigned short* __restrict__ Wl2, int K2,
    const unsigned short* __restrict__ Hh, const unsigned short* __restrict__ Hm,
    const unsigned short* __restrict__ Hl,
    const float* __restrict__ biasI,
    const float* __restrict__ c_in, float* __restrict__ h_out,
    float* __restrict__ c_out, int czero)
{
    __shared__ __align__(16) unsigned short wlds[2][3 * 4096]; // 48 KB

    const int tid = threadIdx.x;
    const int wv = tid >> 6, lane = tid & 63;
    const int wm = wv & 1, wn = wv >> 1;
    const int lm = lane & 15, quad = lane >> 4;
    const int c0 = blockIdx.y * 128;             // block n-panel base row
    const int nT = c0 + wn * 64;                 // wave output-channel base
    const int mB = blockIdx.x * 128 + wm * 64;   // batch tile base

    // per-lane activation row pointers (4 m-tiles)
    int mrow[4];
    const float* xr[4];
    size_t hoff[4];
#pragma unroll
    for (int tm = 0; tm < 4; ++tm) {
        int m = mB + tm * 16 + lm;
        mrow[tm] = m;
        if (X) {
            size_t off = (size_t)m * ldx;
            if (gather) off += (size_t)gather[m] * gmul;
            xr[tm] = X + off;
        }
        hoff[tm] = (size_t)m * K2;
    }

    // ---- staging geometry: thread (w, L) stages rows seg*16 + L/4, i in {0,1}
    int srow[2], sqs[2];
#pragma unroll
    for (int i = 0; i < 2; ++i) {
        const int seg = i * 4 + wv;
        const int r = seg * 16 + (lane >> 2);
        srow[i] = r;
        sqs[i] = (lane & 3) ^ ((r >> 1) & 3);    // pre-swizzled source chunk
    }
    size_t roff1[2], roff2[2];                   // per-part row offsets (elems)
#pragma unroll
    for (int i = 0; i < 2; ++i) {
        roff1[i] = (size_t)(c0 + srow[i]) * K1 + (size_t)(sqs[i] * 8);
        roff2[i] = (size_t)(c0 + srow[i]) * K2 + (size_t)(sqs[i] * 8);
    }

    // ---- ds_read fragment offsets (ushort units; constant across chunks)
    int boffW[4];
#pragma unroll
    for (int tn = 0; tn < 4; ++tn) {
        const int r = wn * 64 + tn * 16 + lm;
        boffW[tn] = r * 32 + ((quad ^ ((r >> 1) & 3)) * 8);
    }

    // stage weight planes for absolute chunk kcN into wlds[buf]
    auto stage = [&](int kcN, int buf) {
        const bool nX = kcN < K1;
        const int kb = nX ? kcN : kcN - K1;
#pragma unroll
        for (int i = 0; i < 2; ++i) {
            const int seg = i * 4 + wv;
            unsigned short* lb = &wlds[buf][seg * 512];
            const unsigned short* gh = (nX ? Wh1 + roff1[i] : Wh2 + roff2[i]) + kb;
            const unsigned short* gm = (nX ? Wm1 + roff1[i] : Wm2 + roff2[i]) + kb;
            const unsigned short* gl = (nX ? Wl1 + roff1[i] : Wl2 + roff2[i]) + kb;
            __builtin_amdgcn_global_load_lds(
                (const __attribute__((address_space(1))) void*)gh,
                (__attribute__((address_space(3))) void*)(lb), 16, 0, 0);
            __builtin_amdgcn_global_load_lds(
                (const __attribute__((address_space(1))) void*)gm,
                (__attribute__((address_space(3))) void*)(lb + 4096), 16, 0, 0);
            __builtin_amdgcn_global_load_lds(
                (const __attribute__((address_space(1))) void*)gl,
                (__attribute__((address_space(3))) void*)(lb + 8192), 16, 0, 0);
        }
    };

    f32x4 acc[4][4];
#pragma unroll
    for (int i = 0; i < 4; ++i)
#pragma unroll
        for (int j = 0; j < 4; ++j) acc[i][j] = (f32x4){0.f, 0.f, 0.f, 0.f};

    const int KT = K1 + K2;
    stage(0, 0);
    int cur = 0;

    for (int kc = 0; kc < KT; kc += 32) {
        __syncthreads();                       // drains staged loads for buf[cur]
        if (kc + 32 < KT) stage(kc + 32, cur ^ 1);

        const bool inX = kc < K1;
        const int kk = (inX ? kc : kc - K1) + quad * 8;

        // weight fragments from LDS (swizzled ds_read_b128, conflict-free)
        const unsigned short* bufp = wlds[cur];
        bfrag8 ah[4], am4[4], al[4];
#pragma unroll
        for (int tn = 0; tn < 4; ++tn) {
            ah[tn]  = *(const bfrag8*)(bufp + boffW[tn]);
            am4[tn] = *(const bfrag8*)(bufp + 4096 + boffW[tn]);
            al[tn]  = *(const bfrag8*)(bufp + 8192 + boffW[tn]);
        }

        if (inX) {
            // X part: fp32 activations, split3 in VALU (4 of 20 chunks)
#pragma unroll
            for (int tm = 0; tm < 4; ++tm) {
                const float* p = xr[tm] + kk;
                float a8[8];
                *(float4*)&a8[0] = *(const float4*)(p);
                *(float4*)&a8[4] = *(const float4*)(p + 4);
                bfrag8 bh, bm, bl;
#pragma unroll
                for (int j = 0; j < 8; ++j) {
                    unsigned short h, m, l;
                    split3(a8[j], h, m, l);
                    bh[j] = (short)h; bm[j] = (short)m; bl[j] = (short)l;
                }
#pragma unroll
                for (int tn = 0; tn < 4; ++tn) {
                    f32x4 c = acc[tn][tm];
                    c = __builtin_amdgcn_mfma_f32_16x16x32_bf16(ah[tn], bl, c, 0, 0, 0);
                    c = __builtin_amdgcn_mfma_f32_16x16x32_bf16(al[tn], bh, c, 0, 0, 0);
                    c = __builtin_amdgcn_mfma_f32_16x16x32_bf16(am4[tn], bm, c, 0, 0, 0);
                    c = __builtin_amdgcn_mfma_f32_16x16x32_bf16(ah[tn], bm, c, 0, 0, 0);
                    c = __builtin_amdgcn_mfma_f32_16x16x32_bf16(am4[tn], bh, c, 0, 0, 0);
                    c = __builtin_amdgcn_mfma_f32_16x16x32_bf16(ah[tn], bh, c, 0, 0, 0);
                    acc[tn][tm] = c;
                }
            }
        } else {
            // H part: pre-split bf16 planes, zero VALU (16 of 20 chunks)
#pragma unroll
            for (int tm = 0; tm < 4; ++tm) {
                bfrag8 bh = *(const bfrag8*)(Hh + hoff[tm] + kk);
                bfrag8 bm = *(const bfrag8*)(Hm + hoff[tm] + kk);
                bfrag8 bl = *(const bfrag8*)(Hl + hoff[tm] + kk);
#pragma unroll
                for (int tn = 0; tn < 4; ++tn) {
                    f32x4 c = acc[tn][tm];
                    c = __builtin_amdgcn_mfma_f32_16x16x32_bf16(ah[tn], bl, c, 0, 0, 0);
                    c = __builtin_amdgcn_mfma_f32_16x16x32_bf16(al[tn], bh, c, 0, 0, 0);
                    c = __builtin_amdgcn_mfma_f32_16x16x32_bf16(am4[tn], bm, c, 0, 0, 0);
                    c = __builtin_amdgcn_mfma_f32_16x16x32_bf16(ah[tn], bm, c, 0, 0, 0);
                    c = __builtin_amdgcn_mfma_f32_16x16x32_bf16(am4[tn], bh, c, 0, 0, 0);
                    c = __builtin_amdgcn_mfma_f32_16x16x32_bf16(ah[tn], bh, c, 0, 0, 0);
                    acc[tn][tm] = c;
                }
            }
        }
        cur ^= 1;
    }

    // fused LSTM epilogue: lane's 4 acc regs = gates i,f,g,o of unit j
#pragma unroll
    for (int tn = 0; tn < 4; ++tn) {
        const int nb = nT + tn * 16 + quad * 4;
        float4 bb = *(const float4*)(biasI + nb);
        const int j = nb >> 2;
#pragma unroll
        for (int tm = 0; tm < 4; ++tm) {
            const size_t idx = (size_t)mrow[tm] * Hdim + j;
            float gi = acc[tn][tm][0] + bb.x;
            float gf = acc[tn][tm][1] + bb.y;
            float gg = acc[tn][tm][2] + bb.z;
            float go = acc[tn][tm][3] + bb.w;
            float si = 1.f / (1.f + expf(-gi));
            float sf = 1.f / (1.f + expf(-gf));
            float so = 1.f / (1.f + expf(-go));
            float co = czero ? 0.f : c_in[idx];
            float cn = si * tanhf(gg) + sf * co;
            c_out[idx] = cn;
            h_out[idx] = so * tanhf(cn);
        }
    }
}

// ---------------------------------------------------------------------------
// Small fp32 GEMM: C = A @ W^T + bias (4096x512, K=512). 64x64 tile, 256
// threads, 2x2 waves, per-lane 4x4 (52 VGPR, proven). Grid (8,64)=512=2/CU.
// Used for u2 (Wref2) and qp (Wq2).
// ---------------------------------------------------------------------------
__global__ __launch_bounds__(256, 4) void gemm_sm(const float* __restrict__ A,
                                                  const float* __restrict__ W,
                                                  const float* __restrict__ bias,
                                                  float* __restrict__ C, int ldc)
{
    __shared__ float As[BK][64];
    __shared__ float Bs[BK][64];
    const int tid = threadIdx.x;
    const int rowBase = blockIdx.y * 64;
    const int colBase = blockIdx.x * 64;
    const int wv = tid >> 6;
    const int waveX = wv & 1, waveY = wv >> 1;
    const int lane = tid & 63;
    const int lx = lane & 7, ly = lane >> 3;
    const int rOff = waveY * 32 + ly * 4;
    const int cOff = waveX * 32 + lx * 4;

    const int ra = tid & 63;
    const int ka = (tid >> 6) * 4;
    const float* arow = A + (size_t)(rowBase + ra) * Hdim + ka;
    const float* brow = W + (size_t)(colBase + ra) * Hdim + ka;

    float4 aR, bR;
    float acc[4][4];
#pragma unroll
    for (int i = 0; i < 4; ++i)
#pragma unroll
        for (int j = 0; j < 4; ++j) acc[i][j] = 0.f;

    aR = *(const float4*)(arow);
    bR = *(const float4*)(brow);
    for (int kt = 0; kt < Hdim; kt += BK) {
        __syncthreads();
        As[ka + 0][ra] = aR.x; As[ka + 1][ra] = aR.y;
        As[ka + 2][ra] = aR.z; As[ka + 3][ra] = aR.w;
        Bs[ka + 0][ra] = bR.x; Bs[ka + 1][ra] = bR.y;
        Bs[ka + 2][ra] = bR.z; Bs[ka + 3][ra] = bR.w;
        __syncthreads();
        if (kt + BK < Hdim) {
            aR = *(const float4*)(arow + kt + BK);
            bR = *(const float4*)(brow + kt + BK);
        }
#pragma unroll
        for (int kk = 0; kk < BK; ++kk) {
            float4 av = *(const float4*)&As[kk][rOff];
            float4 bv = *(const float4*)&Bs[kk][cOff];
            const float* ap = (const float*)&av;
            const float* bp = (const float*)&bv;
#pragma unroll
            for (int i = 0; i < 4; ++i)
#pragma unroll
                for (int j = 0; j < 4; ++j) acc[i][j] += ap[i] * bp[j];
        }
    }

    float4 bb = *(const float4*)(bias + colBase + cOff);
#pragma unroll
    for (int i = 0; i < 4; ++i) {
        const int row = rowBase + rOff + i;
        float4 o;
        o.x = acc[i][0] + bb.x;
        o.y = acc[i][1] + bb.y;
        o.z = acc[i][2] + bb.z;
        o.w = acc[i][3] + bb.w;
        *(float4*)(C + (size_t)row * ldc + colBase + cOff) = o;
    }
}

// ---------------------------------------------------------------------------
// Attention + log-softmax + argmax + state update.
// ---------------------------------------------------------------------------
__global__ __launch_bounds__(256) void attn_step(const float* __restrict__ qp,
                                                 const float* __restrict__ u2,
                                                 const float* __restrict__ Vec2,
                                                 float* __restrict__ mask,
                                                 float* __restrict__ ll_ws,
                                                 int* __restrict__ nxt,
                                                 float* __restrict__ out_map,
                                                 float* __restrict__ out_ll,
                                                 int step, int node) {
    const int b = blockIdx.x;
    __shared__ float qpS[Hdim];
    __shared__ float vS[Hdim];
    __shared__ float logitS[Sseq];
    const int tid = threadIdx.x;
    qpS[tid]       = qp[(size_t)b * Hdim + tid];
    qpS[tid + 256] = qp[(size_t)b * Hdim + 256 + tid];
    vS[tid]        = Vec2[tid];
    vS[tid + 256]  = Vec2[256 + tid];
    __syncthreads();

    const int wave = tid >> 6, lane = tid & 63;
    for (int si = 0; si < 4; ++si) {
        int s = wave * 4 + si;
        const float* u2p = u2 + ((size_t)b * Sseq + s) * Hdim;
        float sum = 0.f;
#pragma unroll
        for (int i = 0; i < 8; ++i) {
            int hh = lane + i * 64;
            sum += vS[hh] * tanhf(qpS[hh] + u2p[hh]);
        }
        for (int off = 32; off > 0; off >>= 1) sum += __shfl_down(sum, off);
        if (lane == 0) {
            float pen = step ? mask[b * Sseq + s] * 1e8f : 0.f;
            logitS[s] = 10.f * sum - pen;
        }
    }
    __syncthreads();

    if (tid == 0) {
        float mx = logitS[0];
        int am = 0;
        for (int s = 1; s < Sseq; ++s)
            if (logitS[s] > mx) { mx = logitS[s]; am = s; }
        float se = 0.f;
        for (int s = 0; s < Sseq; ++s) se += expf(logitS[s] - mx);
        float lp = -logf(se);
        float llv = (step ? ll_ws[b] : 0.f) + lp;
        ll_ws[b] = llv;
        out_ll[b] = llv;
        nxt[b] = am;
        if (step == 0) {
            for (int s = 0; s < Sseq; ++s) mask[b * Sseq + s] = (s == am) ? 1.f : 0.f;
        } else {
            mask[b * Sseq + am] += 1.f;
        }
        out_map[b * Sseq + am] = (float)node;
    }
}

// ---------------------------------------------------------------------------
extern "C" void kernel_launch(void* const* d_in, const int* in_sizes, int n_in,
                              void* d_out, int out_size, void* d_ws, size_t ws_size,
                              hipStream_t stream) {
    const float* x       = (const float*)d_in[0];
    const float* emb_W   = (const float*)d_in[1];
    const float* enc_Wih = (const float*)d_in[2];
    const float* enc_Whh = (const float*)d_in[3];
    const float* enc_b   = (const float*)d_in[4];
    const float* dec_Wih = (const float*)d_in[5];
    const float* dec_Whh = (const float*)d_in[6];
    const float* dec_b   = (const float*)d_in[7];
    const float* Wq2     = (const float*)d_in[8];
    const float* bq2     = (const float*)d_in[9];
    const float* Wref2   = (const float*)d_in[10];
    const float* bref2   = (const float*)d_in[11];
    const float* Vec2    = (const float*)d_in[12];
    const float* dec0    = (const float*)d_in[13];

    // workspace layout — ~217 MB
    float* ws      = (float*)d_ws;
    float* u2      = ws;                                   // B*S*H fp32
    float* h0      = u2 + (size_t)Bsz * Sseq * Hdim;       // B*H each
    float* c0      = h0 + (size_t)Bsz * Hdim;
    float* h1      = c0 + (size_t)Bsz * Hdim;
    float* c1      = h1 + (size_t)Bsz * Hdim;
    float* qp      = c1 + (size_t)Bsz * Hdim;
    float* mask    = qp + (size_t)Bsz * Hdim;              // B*S
    float* ll      = mask + (size_t)Bsz * Sseq;            // B
    int*   nxt     = (int*)(ll + Bsz);                     // B
    float* encBI   = (float*)(nxt + Bsz);                  // 2048 each
    float* decBI   = encBI + H4;
    float* v0bI    = decBI + H4;
    // bf16 weight planes (ushort)
    unsigned short* us = (unsigned short*)(v0bI + H4);
    unsigned short* encEh = us;                       us += (size_t)H4 * Gdim;
    unsigned short* encEm = us;                       us += (size_t)H4 * Gdim;
    unsigned short* encEl = us;                       us += (size_t)H4 * Gdim;
    unsigned short* encWh = us;                       us += (size_t)H4 * Hdim;
    unsigned short* encWm = us;                       us += (size_t)H4 * Hdim;
    unsigned short* encWl = us;                       us += (size_t)H4 * Hdim;
    unsigned short* decEh = us;                       us += (size_t)H4 * Gdim;
    unsigned short* decEm = us;                       us += (size_t)H4 * Gdim;
    unsigned short* decEl = us;                       us += (size_t)H4 * Gdim;
    unsigned short* decWh = us;                       us += (size_t)H4 * Hdim;
    unsigned short* decWm = us;                       us += (size_t)H4 * Hdim;
    unsigned short* decWl = us;                       us += (size_t)H4 * Hdim;
    // bf16 h activation planes, ping-pong (B*H ushort each, +24 MB)
    unsigned short* h0h = us;                         us += (size_t)Bsz * Hdim;
    unsigned short* h0m = us;                         us += (size_t)Bsz * Hdim;
    unsigned short* h0l = us;                         us += (size_t)Bsz * Hdim;
    unsigned short* h1h = us;                         us += (size_t)Bsz * Hdim;
    unsigned short* h1m = us;                         us += (size_t)Bsz * Hdim;
    unsigned short* h1l = us;                         us += (size_t)Bsz * Hdim;

    float* out_map = (float*)d_out;                        // B*P floats
    float* out_ll  = out_map + (size_t)Bsz * Psteps;       // B floats

    static const int nodes[Psteps] = {0,0,0,0, 1,1,1,1, 2,2,2,2, 3,3,3,3};

    fold_kernel<<<H4, Gdim, 0, stream>>>(enc_Wih, enc_Whh, enc_b,
                                         dec_Wih, dec_Whh, dec_b,
                                         emb_W, dec0,
                                         encEh, encEm, encEl, encWh, encWm, encWl,
                                         decEh, decEm, decEl, decWh, decWm, decWl,
                                         encBI, decBI, v0bI);

    const dim3 gBig(32, 16);    // m-blocks x n-blocks = 512 = 2/CU
    const dim3 gSm(8, 64);      // 512 blocks = 2/CU
    const int  gSplit = (Bsz * Hdim) / 8 / 256;   // 1024 blocks

    // ---- encoder: 16 fused LSTM steps + plane split + u2[t] projection ----
    for (int t = 0; t < Sseq; ++t) {
        float* ho = (t & 1) ? h0 : h1;
        float* co = (t & 1) ? c0 : c1;
        const float* ci = (t & 1) ? c1 : c0;
        unsigned short* hoh = (t & 1) ? h0h : h1h;
        unsigned short* hom = (t & 1) ? h0m : h1m;
        unsigned short* hol = (t & 1) ? h0l : h1l;
        const unsigned short* hih = (t & 1) ? h1h : h0h;
        const unsigned short* him = (t & 1) ? h1m : h0m;
        const unsigned short* hil = (t & 1) ? h1l : h0l;
        if (t == 0) {
            gates_mfma<<<gBig, 256, 0, stream>>>(
                encEh, encEm, encEl, Gdim,
                x, Sseq * Gdim, nullptr, 0,
                nullptr, nullptr, nullptr, 0,
                nullptr, nullptr, nullptr,
                encBI, ci, ho, co, 1);
        } else {
            gates_mfma<<<gBig, 256, 0, stream>>>(
                encEh, encEm, encEl, Gdim,
                x + t * Gdim, Sseq * Gdim, nullptr, 0,
                encWh, encWm, encWl, Hdim,
                hih, him, hil,
                encBI, ci, ho, co, 0);
        }
        split_planes<<<gSplit, 256, 0, stream>>>(ho, hoh, hom, hol);
        gemm_sm<<<gSm, 256, 0, stream>>>(ho, Wref2, bref2,
                                         u2 + (size_t)t * Hdim, Sseq * Hdim);
    }

    // ---- decoder: 16 autoregressive steps ----
    for (int p = 0; p < Psteps; ++p) {
        const int u = Sseq + p;
        float* ho = (u & 1) ? h0 : h1;
        float* co = (u & 1) ? c0 : c1;
        const float* ci = (u & 1) ? c1 : c0;
        unsigned short* hoh = (u & 1) ? h0h : h1h;
        unsigned short* hom = (u & 1) ? h0m : h1m;
        unsigned short* hol = (u & 1) ? h0l : h1l;
        const unsigned short* hih = (u & 1) ? h1h : h0h;
        const unsigned short* him = (u & 1) ? h1m : h0m;
        const unsigned short* hil = (u & 1) ? h1l : h0l;
        if (p == 0) {
            gates_mfma<<<gBig, 256, 0, stream>>>(
                nullptr, nullptr, nullptr, 0,
                nullptr, 0, nullptr, 0,
                decWh, decWm, decWl, Hdim,
                hih, him, hil,
                v0bI, ci, ho, co, 0);
        } else {
            gates_mfma<<<gBig, 256, 0, stream>>>(
                decEh, decEm, decEl, Gdim,
                x, Sseq * Gdim, nxt, Gdim,
                decWh, decWm, decWl, Hdim,
                hih, him, hil,
                decBI, ci, ho, co, 0);
        }
        if (p < Psteps - 1)  // last h has no consumer
            split_planes<<<gSplit, 256, 0, stream>>>(ho, hoh, hom, hol);
        gemm_sm<<<gSm, 256, 0, stream>>>(ho, Wq2, bq2, qp, Hdim);
        attn_step<<<Bsz, 256, 0, stream>>>(qp, u2, Vec2, mask, ll, nxt,
                                           out_map, out_ll, p, nodes[p]);
    }
}

// Round 9
// 3831.050 us; speedup vs baseline: 1.3699x; 1.1909x over previous
//
#include <hip/hip_runtime.h>
#include <cstddef>

// Problem constants
#define Bsz  4096
#define Sseq 16
#define Gdim 128
#define Edim 256
#define Hdim 512
#define H4   2048
#define Psteps 16
#define BK   16

typedef short bfrag8 __attribute__((ext_vector_type(8)));   // 8 bf16 (4 VGPR)
typedef float f32x4  __attribute__((ext_vector_type(4)));   // MFMA acc

// Exact 3-way bf16 split of fp32 (truncation; residuals exactly representable:
// 24 mantissa bits = 8+8+8). a == hi+mid+lo exactly (normal range).
__device__ __forceinline__ void split3(float f, unsigned short& h,
                                       unsigned short& m, unsigned short& l) {
    unsigned u = __float_as_uint(f);
    h = (unsigned short)(u >> 16);
    float r1 = f - __uint_as_float(u & 0xffff0000u);
    unsigned u1 = __float_as_uint(r1);
    m = (unsigned short)(u1 >> 16);
    float r2 = r1 - __uint_as_float(u1 & 0xffff0000u);
    l = (unsigned short)(__float_as_uint(r2) >> 16);
}

// ---------------------------------------------------------------------------
// Fold kernel: gate-interleaved (row c = j*4+gate) weight prep, emitting
// bf16 hi/mid/lo planes for the MFMA path.
// ---------------------------------------------------------------------------
__global__ void fold_kernel(const float* __restrict__ encWih,
                            const float* __restrict__ encWhh,
                            const float* __restrict__ enc_b,
                            const float* __restrict__ decWih,
                            const float* __restrict__ decWhh,
                            const float* __restrict__ dec_b,
                            const float* __restrict__ embW,
                            const float* __restrict__ dec0,
                            unsigned short* __restrict__ encEh,
                            unsigned short* __restrict__ encEm,
                            unsigned short* __restrict__ encEl,
                            unsigned short* __restrict__ encWh,
                            unsigned short* __restrict__ encWm,
                            unsigned short* __restrict__ encWl,
                            unsigned short* __restrict__ decEh,
                            unsigned short* __restrict__ decEm,
                            unsigned short* __restrict__ decEl,
                            unsigned short* __restrict__ decWh,
                            unsigned short* __restrict__ decWm,
                            unsigned short* __restrict__ decWl,
                            float* __restrict__ encBI, float* __restrict__ decBI,
                            float* __restrict__ v0bI) {
    const int o = blockIdx.x;            // original row 0..2047 (gate*512 + j)
    const int gate = o >> 9, j = o & 511;
    const int c = j * 4 + gate;          // interleaved row
    const int g = threadIdx.x;           // 0..127
    float se = 0.f, sd = 0.f;
    for (int e = 0; e < Edim; ++e) {
        float w = embW[e * Gdim + g];
        se += encWih[(size_t)o * Edim + e] * w;
        sd += decWih[(size_t)o * Edim + e] * w;
    }
    unsigned short h, m, l;
    split3(se, h, m, l);
    encEh[(size_t)c * Gdim + g] = h; encEm[(size_t)c * Gdim + g] = m;
    encEl[(size_t)c * Gdim + g] = l;
    split3(sd, h, m, l);
    decEh[(size_t)c * Gdim + g] = h; decEm[(size_t)c * Gdim + g] = m;
    decEl[(size_t)c * Gdim + g] = l;
    for (int k = g; k < Hdim; k += Gdim) {
        split3(encWhh[(size_t)o * Hdim + k], h, m, l);
        encWh[(size_t)c * Hdim + k] = h; encWm[(size_t)c * Hdim + k] = m;
        encWl[(size_t)c * Hdim + k] = l;
        split3(decWhh[(size_t)o * Hdim + k], h, m, l);
        decWh[(size_t)c * Hdim + k] = h; decWm[(size_t)c * Hdim + k] = m;
        decWl[(size_t)c * Hdim + k] = l;
    }
    if (g == 0) {
        encBI[c] = enc_b[o];
        decBI[c] = dec_b[o];
        float s = dec_b[o];
        for (int e = 0; e < Edim; ++e) s += decWih[(size_t)o * Edim + e] * dec0[e];
        v0bI[c] = s;
    }
}

// ---------------------------------------------------------------------------
// MFMA gates GEMM + fused LSTM epilogue, fp32-exact via bf16x6 emulation.
// Round-9: round-4 structure restored (best measured: 84.2us, rounds 1/8's
// plane experiments and rounds 3/5's prefetch experiments all refuted).
// ONE change: ACTIVATIONS also go through the double-buffered LDS staging
// (fp32, 128 rows x 32 k = 16 KB/chunk, global_load_lds issued one chunk
// ahead). This removes the 2x redundant per-wave scattered global activation
// reads (wn-pair waves loaded identical fragments every chunk) and hides
// their L2 latency behind a full chunk of MFMA. 32B-slot XOR swizzle
// (slot ^= row&3) applied on BOTH sides: inverse-swizzled per-lane global
// source (works for the decode gather path too), swizzled ds_read address.
// split3 values, MFMA order, epilogue unchanged -> bit-identical output.
// LDS/block = 48K (weights) + 32K (acts) = 80KB -> 2 blocks/CU as before.
// ---------------------------------------------------------------------------
__global__ __launch_bounds__(256) void gates_mfma(
    const unsigned short* __restrict__ Wh1, const unsigned short* __restrict__ Wm1,
    const unsigned short* __restrict__ Wl1, int K1,
    const float* __restrict__ X, int ldx,
    const int* __restrict__ gather, int gmul,
    const unsigned short* __restrict__ Wh2, const unsigned short* __restrict__ Wm2,
    const unsigned short* __restrict__ Wl2, int K2,
    const float* __restrict__ Hin,
    const float* __restrict__ biasI,
    const float* __restrict__ c_in, float* __restrict__ h_out,
    float* __restrict__ c_out, int czero)
{
    __shared__ __align__(16) unsigned short wlds[2][3 * 4096]; // 48 KB
    __shared__ __align__(16) float alds[2][128 * 32];          // 32 KB

    const int tid = threadIdx.x;
    const int wv = tid >> 6, lane = tid & 63;
    const int wm = wv & 1, wn = wv >> 1;
    const int lm = lane & 15, quad = lane >> 4;
    const int c0 = blockIdx.y * 128;             // block n-panel base row
    const int nT = c0 + wn * 64;                 // wave output-channel base
    const int mB0 = blockIdx.x * 128;            // block batch base (128 rows)

    // per-lane output rows (epilogue)
    int mrow[4];
#pragma unroll
    for (int tm = 0; tm < 4; ++tm) mrow[tm] = mB0 + wm * 64 + tm * 16 + lm;

    // ---- weight staging geometry (unchanged from round-4) ----
    int srow[2], sqs[2];
#pragma unroll
    for (int i = 0; i < 2; ++i) {
        const int seg = i * 4 + wv;
        const int r = seg * 16 + (lane >> 2);
        srow[i] = r;
        sqs[i] = (lane & 3) ^ ((r >> 1) & 3);    // pre-swizzled source chunk
    }
    size_t roff1[2], roff2[2];                   // per-part row offsets (elems)
#pragma unroll
    for (int i = 0; i < 2; ++i) {
        roff1[i] = (size_t)(c0 + srow[i]) * K1 + (size_t)(sqs[i] * 8);
        roff2[i] = (size_t)(c0 + srow[i]) * K2 + (size_t)(sqs[i] * 8);
    }

    // ---- activation staging geometry: 16 segments x 8 rows x 32 floats ----
    // lane l in segment: row r = seg*8 + (l>>3); 16B unit u = l&7; 32B slot
    // p = u>>1, half = u&1. Stored slot p holds logical slot q = p ^ (r&3)
    // -> per-lane source float offset = (p^(r&3))*8 + half*4.
    const float* asrcX[4];
    const float* asrcH[4];
#pragma unroll
    for (int i = 0; i < 4; ++i) {
        const int r = (wv * 4 + i) * 8 + (lane >> 3);
        const int u = lane & 7;
        const int sw = (((u >> 1) ^ (r & 3)) << 3) + (u & 1) * 4;
        const int m = mB0 + r;
        if (X) {
            size_t off = (size_t)m * ldx;
            if (gather) off += (size_t)gather[m] * gmul;
            asrcX[i] = X + off + sw;
        }
        if (Hin) asrcH[i] = Hin + (size_t)m * K2 + sw;
    }

    // ---- ds_read fragment offsets (ushort units; constant across chunks)
    int boffW[4];
#pragma unroll
    for (int tn = 0; tn < 4; ++tn) {
        const int r = wn * 64 + tn * 16 + lm;
        boffW[tn] = r * 32 + ((quad ^ ((r >> 1) & 3)) * 8);
    }
    // activation ds_read offsets (float units; constant across chunks)
    int boffA[4];
#pragma unroll
    for (int tm = 0; tm < 4; ++tm) {
        const int r = wm * 64 + tm * 16 + lm;
        boffA[tm] = r * 32 + ((quad ^ (r & 3)) << 3);
    }

    // stage weight + activation windows for absolute chunk kcN into buf
    auto stage = [&](int kcN, int buf) {
        const bool nX = kcN < K1;
        const int kb = nX ? kcN : kcN - K1;
#pragma unroll
        for (int i = 0; i < 2; ++i) {
            const int seg = i * 4 + wv;
            unsigned short* lb = &wlds[buf][seg * 512];
            const unsigned short* gh = (nX ? Wh1 + roff1[i] : Wh2 + roff2[i]) + kb;
            const unsigned short* gm = (nX ? Wm1 + roff1[i] : Wm2 + roff2[i]) + kb;
            const unsigned short* gl = (nX ? Wl1 + roff1[i] : Wl2 + roff2[i]) + kb;
            __builtin_amdgcn_global_load_lds(
                (const __attribute__((address_space(1))) void*)gh,
                (__attribute__((address_space(3))) void*)(lb), 16, 0, 0);
            __builtin_amdgcn_global_load_lds(
                (const __attribute__((address_space(1))) void*)gm,
                (__attribute__((address_space(3))) void*)(lb + 4096), 16, 0, 0);
            __builtin_amdgcn_global_load_lds(
                (const __attribute__((address_space(1))) void*)gl,
                (__attribute__((address_space(3))) void*)(lb + 8192), 16, 0, 0);
        }
#pragma unroll
        for (int i = 0; i < 4; ++i) {
            float* lb = &alds[buf][(wv * 4 + i) * 256];
            const float* src = (nX ? asrcX[i] : asrcH[i]) + kb;
            __builtin_amdgcn_global_load_lds(
                (const __attribute__((address_space(1))) void*)src,
                (__attribute__((address_space(3))) void*)lb, 16, 0, 0);
        }
    };

    f32x4 acc[4][4];
#pragma unroll
    for (int i = 0; i < 4; ++i)
#pragma unroll
        for (int j = 0; j < 4; ++j) acc[i][j] = (f32x4){0.f, 0.f, 0.f, 0.f};

    const int KT = K1 + K2;
    stage(0, 0);
    int cur = 0;

    for (int kc = 0; kc < KT; kc += 32) {
        __syncthreads();                       // drains staged loads for buf[cur]
        if (kc + 32 < KT) stage(kc + 32, cur ^ 1);

        // weight fragments from LDS (swizzled ds_read_b128, conflict-free)
        const unsigned short* bufp = wlds[cur];
        bfrag8 ah[4], am4[4], al[4];
#pragma unroll
        for (int tn = 0; tn < 4; ++tn) {
            ah[tn]  = *(const bfrag8*)(bufp + boffW[tn]);
            am4[tn] = *(const bfrag8*)(bufp + 4096 + boffW[tn]);
            al[tn]  = *(const bfrag8*)(bufp + 8192 + boffW[tn]);
        }

        const float* abuf = alds[cur];
#pragma unroll
        for (int tm = 0; tm < 4; ++tm) {
            float a8[8];
            *(float4*)&a8[0] = *(const float4*)(abuf + boffA[tm]);
            *(float4*)&a8[4] = *(const float4*)(abuf + boffA[tm] + 4);
            bfrag8 bh, bm, bl;
#pragma unroll
            for (int j = 0; j < 8; ++j) {
                unsigned short h, m, l;
                split3(a8[j], h, m, l);
                bh[j] = (short)h; bm[j] = (short)m; bl[j] = (short)l;
            }
#pragma unroll
            for (int tn = 0; tn < 4; ++tn) {
                f32x4 c = acc[tn][tm];
                c = __builtin_amdgcn_mfma_f32_16x16x32_bf16(ah[tn], bl, c, 0, 0, 0);
                c = __builtin_amdgcn_mfma_f32_16x16x32_bf16(al[tn], bh, c, 0, 0, 0);
                c = __builtin_amdgcn_mfma_f32_16x16x32_bf16(am4[tn], bm, c, 0, 0, 0);
                c = __builtin_amdgcn_mfma_f32_16x16x32_bf16(ah[tn], bm, c, 0, 0, 0);
                c = __builtin_amdgcn_mfma_f32_16x16x32_bf16(am4[tn], bh, c, 0, 0, 0);
                c = __builtin_amdgcn_mfma_f32_16x16x32_bf16(ah[tn], bh, c, 0, 0, 0);
                acc[tn][tm] = c;
            }
        }
        cur ^= 1;
    }

    // fused LSTM epilogue: lane's 4 acc regs = gates i,f,g,o of unit j
#pragma unroll
    for (int tn = 0; tn < 4; ++tn) {
        const int nb = nT + tn * 16 + quad * 4;
        float4 bb = *(const float4*)(biasI + nb);
        const int j = nb >> 2;
#pragma unroll
        for (int tm = 0; tm < 4; ++tm) {
            const size_t idx = (size_t)mrow[tm] * Hdim + j;
            float gi = acc[tn][tm][0] + bb.x;
            float gf = acc[tn][tm][1] + bb.y;
            float gg = acc[tn][tm][2] + bb.z;
            float go = acc[tn][tm][3] + bb.w;
            float si = 1.f / (1.f + expf(-gi));
            float sf = 1.f / (1.f + expf(-gf));
            float so = 1.f / (1.f + expf(-go));
            float co = czero ? 0.f : c_in[idx];
            float cn = si * tanhf(gg) + sf * co;
            c_out[idx] = cn;
            h_out[idx] = so * tanhf(cn);
        }
    }
}

// ---------------------------------------------------------------------------
// Small fp32 GEMM: C = A @ W^T + bias (4096x512, K=512). 64x64 tile, 256
// threads, 2x2 waves, per-lane 4x4 (52 VGPR, proven). Grid (8,64)=512=2/CU.
// Used for u2 (Wref2) and qp (Wq2).
// ---------------------------------------------------------------------------
__global__ __launch_bounds__(256, 4) void gemm_sm(const float* __restrict__ A,
                                                  const float* __restrict__ W,
                                                  const float* __restrict__ bias,
                                                  float* __restrict__ C, int ldc)
{
    __shared__ float As[BK][64];
    __shared__ float Bs[BK][64];
    const int tid = threadIdx.x;
    const int rowBase = blockIdx.y * 64;
    const int colBase = blockIdx.x * 64;
    const int wv = tid >> 6;
    const int waveX = wv & 1, waveY = wv >> 1;
    const int lane = tid & 63;
    const int lx = lane & 7, ly = lane >> 3;
    const int rOff = waveY * 32 + ly * 4;
    const int cOff = waveX * 32 + lx * 4;

    const int ra = tid & 63;
    const int ka = (tid >> 6) * 4;
    const float* arow = A + (size_t)(rowBase + ra) * Hdim + ka;
    const float* brow = W + (size_t)(colBase + ra) * Hdim + ka;

    float4 aR, bR;
    float acc[4][4];
#pragma unroll
    for (int i = 0; i < 4; ++i)
#pragma unroll
        for (int j = 0; j < 4; ++j) acc[i][j] = 0.f;

    aR = *(const float4*)(arow);
    bR = *(const float4*)(brow);
    for (int kt = 0; kt < Hdim; kt += BK) {
        __syncthreads();
        As[ka + 0][ra] = aR.x; As[ka + 1][ra] = aR.y;
        As[ka + 2][ra] = aR.z; As[ka + 3][ra] = aR.w;
        Bs[ka + 0][ra] = bR.x; Bs[ka + 1][ra] = bR.y;
        Bs[ka + 2][ra] = bR.z; Bs[ka + 3][ra] = bR.w;
        __syncthreads();
        if (kt + BK < Hdim) {
            aR = *(const float4*)(arow + kt + BK);
            bR = *(const float4*)(brow + kt + BK);
        }
#pragma unroll
        for (int kk = 0; kk < BK; ++kk) {
            float4 av = *(const float4*)&As[kk][rOff];
            float4 bv = *(const float4*)&Bs[kk][cOff];
            const float* ap = (const float*)&av;
            const float* bp = (const float*)&bv;
#pragma unroll
            for (int i = 0; i < 4; ++i)
#pragma unroll
                for (int j = 0; j < 4; ++j) acc[i][j] += ap[i] * bp[j];
        }
    }

    float4 bb = *(const float4*)(bias + colBase + cOff);
#pragma unroll
    for (int i = 0; i < 4; ++i) {
        const int row = rowBase + rOff + i;
        float4 o;
        o.x = acc[i][0] + bb.x;
        o.y = acc[i][1] + bb.y;
        o.z = acc[i][2] + bb.z;
        o.w = acc[i][3] + bb.w;
        *(float4*)(C + (size_t)row * ldc + colBase + cOff) = o;
    }
}

// ---------------------------------------------------------------------------
// Attention + log-softmax + argmax + state update.
// ---------------------------------------------------------------------------
__global__ __launch_bounds__(256) void attn_step(const float* __restrict__ qp,
                                                 const float* __restrict__ u2,
                                                 const float* __restrict__ Vec2,
                                                 float* __restrict__ mask,
                                                 float* __restrict__ ll_ws,
                                                 int* __restrict__ nxt,
                                                 float* __restrict__ out_map,
                                                 float* __restrict__ out_ll,
                                                 int step, int node) {
    const int b = blockIdx.x;
    __shared__ float qpS[Hdim];
    __shared__ float vS[Hdim];
    __shared__ float logitS[Sseq];
    const int tid = threadIdx.x;
    qpS[tid]       = qp[(size_t)b * Hdim + tid];
    qpS[tid + 256] = qp[(size_t)b * Hdim + 256 + tid];
    vS[tid]        = Vec2[tid];
    vS[tid + 256]  = Vec2[256 + tid];
    __syncthreads();

    const int wave = tid >> 6, lane = tid & 63;
    for (int si = 0; si < 4; ++si) {
        int s = wave * 4 + si;
        const float* u2p = u2 + ((size_t)b * Sseq + s) * Hdim;
        float sum = 0.f;
#pragma unroll
        for (int i = 0; i < 8; ++i) {
            int hh = lane + i * 64;
            sum += vS[hh] * tanhf(qpS[hh] + u2p[hh]);
        }
        for (int off = 32; off > 0; off >>= 1) sum += __shfl_down(sum, off);
        if (lane == 0) {
            float pen = step ? mask[b * Sseq + s] * 1e8f : 0.f;
            logitS[s] = 10.f * sum - pen;
        }
    }
    __syncthreads();

    if (tid == 0) {
        float mx = logitS[0];
        int am = 0;
        for (int s = 1; s < Sseq; ++s)
            if (logitS[s] > mx) { mx = logitS[s]; am = s; }
        float se = 0.f;
        for (int s = 0; s < Sseq; ++s) se += expf(logitS[s] - mx);
        float lp = -logf(se);
        float llv = (step ? ll_ws[b] : 0.f) + lp;
        ll_ws[b] = llv;
        out_ll[b] = llv;
        nxt[b] = am;
        if (step == 0) {
            for (int s = 0; s < Sseq; ++s) mask[b * Sseq + s] = (s == am) ? 1.f : 0.f;
        } else {
            mask[b * Sseq + am] += 1.f;
        }
        out_map[b * Sseq + am] = (float)node;
    }
}

// ---------------------------------------------------------------------------
extern "C" void kernel_launch(void* const* d_in, const int* in_sizes, int n_in,
                              void* d_out, int out_size, void* d_ws, size_t ws_size,
                              hipStream_t stream) {
    const float* x       = (const float*)d_in[0];
    const float* emb_W   = (const float*)d_in[1];
    const float* enc_Wih = (const float*)d_in[2];
    const float* enc_Whh = (const float*)d_in[3];
    const float* enc_b   = (const float*)d_in[4];
    const float* dec_Wih = (const float*)d_in[5];
    const float* dec_Whh = (const float*)d_in[6];
    const float* dec_b   = (const float*)d_in[7];
    const float* Wq2     = (const float*)d_in[8];
    const float* bq2     = (const float*)d_in[9];
    const float* Wref2   = (const float*)d_in[10];
    const float* bref2   = (const float*)d_in[11];
    const float* Vec2    = (const float*)d_in[12];
    const float* dec0    = (const float*)d_in[13];

    // workspace layout — ~192 MB
    float* ws      = (float*)d_ws;
    float* u2      = ws;                                   // B*S*H fp32
    float* h0      = u2 + (size_t)Bsz * Sseq * Hdim;       // B*H each
    float* c0      = h0 + (size_t)Bsz * Hdim;
    float* h1      = c0 + (size_t)Bsz * Hdim;
    float* c1      = h1 + (size_t)Bsz * Hdim;
    float* qp      = c1 + (size_t)Bsz * Hdim;
    float* mask    = qp + (size_t)Bsz * Hdim;              // B*S
    float* ll      = mask + (size_t)Bsz * Sseq;            // B
    int*   nxt     = (int*)(ll + Bsz);                     // B
    float* encBI   = (float*)(nxt + Bsz);                  // 2048 each
    float* decBI   = encBI + H4;
    float* v0bI    = decBI + H4;
    // bf16 weight planes (ushort)
    unsigned short* us = (unsigned short*)(v0bI + H4);
    unsigned short* encEh = us;                       us += (size_t)H4 * Gdim;
    unsigned short* encEm = us;                       us += (size_t)H4 * Gdim;
    unsigned short* encEl = us;                       us += (size_t)H4 * Gdim;
    unsigned short* encWh = us;                       us += (size_t)H4 * Hdim;
    unsigned short* encWm = us;                       us += (size_t)H4 * Hdim;
    unsigned short* encWl = us;                       us += (size_t)H4 * Hdim;
    unsigned short* decEh = us;                       us += (size_t)H4 * Gdim;
    unsigned short* decEm = us;                       us += (size_t)H4 * Gdim;
    unsigned short* decEl = us;                       us += (size_t)H4 * Gdim;
    unsigned short* decWh = us;                       us += (size_t)H4 * Hdim;
    unsigned short* decWm = us;                       us += (size_t)H4 * Hdim;
    unsigned short* decWl = us;                       us += (size_t)H4 * Hdim;

    float* out_map = (float*)d_out;                        // B*P floats
    float* out_ll  = out_map + (size_t)Bsz * Psteps;       // B floats

    static const int nodes[Psteps] = {0,0,0,0, 1,1,1,1, 2,2,2,2, 3,3,3,3};

    fold_kernel<<<H4, Gdim, 0, stream>>>(enc_Wih, enc_Whh, enc_b,
                                         dec_Wih, dec_Whh, dec_b,
                                         emb_W, dec0,
                                         encEh, encEm, encEl, encWh, encWm, encWl,
                                         decEh, decEm, decEl, decWh, decWm, decWl,
                                         encBI, decBI, v0bI);

    const dim3 gBig(32, 16);    // m-blocks x n-blocks = 512 = 2/CU
    const dim3 gSm(8, 64);      // 512 blocks = 2/CU

    // ---- encoder: 16 fused LSTM steps + u2[t] projection of h(t) ----
    for (int t = 0; t < Sseq; ++t) {
        float* ho = (t & 1) ? h0 : h1;
        float* co = (t & 1) ? c0 : c1;
        const float* hi = (t & 1) ? h1 : h0;
        const float* ci = (t & 1) ? c1 : c0;
        if (t == 0) {
            gates_mfma<<<gBig, 256, 0, stream>>>(
                encEh, encEm, encEl, Gdim,
                x, Sseq * Gdim, nullptr, 0,
                nullptr, nullptr, nullptr, 0, nullptr,
                encBI, ci, ho, co, 1);
        } else {
            gates_mfma<<<gBig, 256, 0, stream>>>(
                encEh, encEm, encEl, Gdim,
                x + t * Gdim, Sseq * Gdim, nullptr, 0,
                encWh, encWm, encWl, Hdim, hi,
                encBI, ci, ho, co, 0);
        }
        gemm_sm<<<gSm, 256, 0, stream>>>(ho, Wref2, bref2,
                                         u2 + (size_t)t * Hdim, Sseq * Hdim);
    }

    // ---- decoder: 16 autoregressive steps ----
    for (int p = 0; p < Psteps; ++p) {
        const int u = Sseq + p;
        float* ho = (u & 1) ? h0 : h1;
        float* co = (u & 1) ? c0 : c1;
        const float* hi = (u & 1) ? h1 : h0;
        const float* ci = (u & 1) ? c1 : c0;
        if (p == 0) {
            gates_mfma<<<gBig, 256, 0, stream>>>(
                nullptr, nullptr, nullptr, 0,
                nullptr, 0, nullptr, 0,
                decWh, decWm, decWl, Hdim, hi,
                v0bI, ci, ho, co, 0);
        } else {
            gates_mfma<<<gBig, 256, 0, stream>>>(
                decEh, decEm, decEl, Gdim,
                x, Sseq * Gdim, nxt, Gdim,
                decWh, decWm, decWl, Hdim, hi,
                decBI, ci, ho, co, 0);
        }
        gemm_sm<<<gSm, 256, 0, stream>>>(ho, Wq2, bq2, qp, Hdim);
        attn_step<<<Bsz, 256, 0, stream>>>(qp, u2, Vec2, mask, ll, nxt,
                                           out_map, out_ll, p, nodes[p]);
    }
}